// Round 2
// baseline (828.562 us; speedup 1.0000x reference)
//
#include <hip/hip_runtime.h>
#include <stdint.h>

// GraphBlock_231928234690 — MI355X/gfx950
// All float tensors are FLOAT32 (per reference dtypes). adj is int32.
// Output f32, 256*105*1024 elements. Internal GEMM compute in bf16 MFMA.
//
// Workspace layout (bytes), total ~111.2 MiB:
//   x     @ 0          : 26880*1024 bf16  (concat, for GEMM A + residual)
//   nmask @ 55050240   : 26880 f32
//   qb    @ 55157760   : 256*1024 bf16
//   Wb    @ 55682048   : 24*1024*128 bf16 (W cast)
//   Wt    @ 61973504   : 8*128*1024 bf16  (W[h,2] transposed)
//   qW1t  @ 64070656   : 24*256*1024 bf16
//   qW2t  @ 76653568   : 24*256*256 bf16
//   r_bf  @ 79799296   : 24*256*256 bf16
//   ga    @ 82945024   : 48*256*128 bf16
//   w12   @ 86090752   : 256*48*1024 bf16 (+80-row slack for B-tile overread)
//   F     @ 111420416  : 256*48*105 f32
// h_last staged inside d_out (f32); block (h,n) reads then overwrites its own region.

typedef unsigned short u16;
typedef __bf16 bf16;
typedef __bf16 bf16x8 __attribute__((ext_vector_type(8)));
typedef float f32x4 __attribute__((ext_vector_type(4)));

#define N_ 256
#define E_ 105
#define D_ 1024
#define H_ 8
#define DH_ 128
#define NE_ 26880

__device__ __forceinline__ u16 f2b(float f) { bf16 h = (bf16)f; return __builtin_bit_cast(u16, h); }
__device__ __forceinline__ float b2f(u16 u) { bf16 h = __builtin_bit_cast(bf16, u); return (float)h; }

#define AS1 __attribute__((address_space(1)))
#define AS3 __attribute__((address_space(3)))

__device__ __forceinline__ void load16_lds(const void* g, void* l) {
  __builtin_amdgcn_global_load_lds((AS1 void*)(unsigned long long)(uintptr_t)g,
                                   (AS3 void*)l, 16, 0, 0);
}

// ---------------------------------------------------------------------------
// 128x128 bf16 GEMM tile: C[128r x 128c] = A(128 x K) * B(128 x K)^T
// global_load_lds dwordx4 staging, 3-bit XOR chunk swizzle, ds_read_b128 frags.
// ---------------------------------------------------------------------------
__device__ __forceinline__ void gemm128(const u16* A, const u16* B, int K,
                                        int lda, int ldb, f32x4 (&acc)[4][4]) {
  __shared__ u16 lA[8192];
  __shared__ u16 lB[8192];
  const int tid  = threadIdx.x;
  const int lane = tid & 63;
  const int wave = tid >> 6;
  const int ln15 = lane & 15;
  const int lq   = lane >> 4;
  const int wRow = (wave >> 1) * 64;
  const int wCol = (wave & 1) * 64;

  const int iters = K >> 6;
  for (int kt = 0; kt < iters; ++kt) {
    const char* Ab = (const char*)A + kt * 128;  // kt*64 elems
    const char* Bb = (const char*)B + kt * 128;
#pragma unroll
    for (int m = 0; m < 4; ++m) {
      int ci  = m * 256 + tid;
      int row = ci >> 3;
      int g   = (ci & 7) ^ (row & 7);
      char* dstA = (char*)lA + m * 4096 + wave * 1024;  // wave-uniform base
      char* dstB = (char*)lB + m * 4096 + wave * 1024;
      load16_lds(Ab + (long)row * (lda * 2) + g * 16, dstA);
      load16_lds(Bb + (long)row * (ldb * 2) + g * 16, dstB);
    }
    __syncthreads();
#pragma unroll
    for (int ks = 0; ks < 2; ++ks) {
      const int cc = ks * 4 + lq;
      bf16x8 af[4], bfv[4];
#pragma unroll
      for (int i = 0; i < 4; ++i) {
        int r = wRow + i * 16 + ln15;
        af[i] = *(const bf16x8*)&lA[r * 64 + ((cc ^ (r & 7)) << 3)];
        int c = wCol + i * 16 + ln15;
        bfv[i] = *(const bf16x8*)&lB[c * 64 + ((cc ^ (c & 7)) << 3)];
      }
#pragma unroll
      for (int i = 0; i < 4; ++i)
#pragma unroll
        for (int j = 0; j < 4; ++j)
          acc[i][j] = __builtin_amdgcn_mfma_f32_16x16x32_bf16(af[i], bfv[j], acc[i][j], 0, 0, 0);
    }
    __syncthreads();
  }
}

__device__ __forceinline__ void zero_acc(f32x4 (&acc)[4][4]) {
  f32x4 z = {0.f, 0.f, 0.f, 0.f};
#pragma unroll
  for (int i = 0; i < 4; ++i)
#pragma unroll
    for (int j = 0; j < 4; ++j) acc[i][j] = z;
}

// ---------------------------------------------------------------------------
// k_cast: dst[i] = bf16(src[i]), n multiple of 4
// ---------------------------------------------------------------------------
__global__ __launch_bounds__(256) void k_cast(const float* src, u16* dst, long n) {
  long i = ((long)blockIdx.x * 256 + threadIdx.x) * 4;
  if (i >= n) return;
  float4 v = *(const float4*)(src + i);
  ushort4 o;
  o.x = f2b(v.x); o.y = f2b(v.y); o.z = f2b(v.z); o.w = f2b(v.w);
  *(ushort4*)(dst + i) = o;
}

// ---------------------------------------------------------------------------
// k_build: x = bf16(concat[q, para, sent, ent]), node_mask (f32)
// ---------------------------------------------------------------------------
__global__ __launch_bounds__(256) void k_build(const float* q, const float* para,
                                               const float* sent, const float* ent,
                                               const float* pm, const float* sm,
                                               const float* em, u16* x, float* nmask) {
  long idx = (long)blockIdx.x * 256 + threadIdx.x;
  if (idx >= (long)NE_ * 128) return;
  int ne = (int)(idx >> 7), dc = (int)(idx & 127);
  int n = ne / E_, e = ne - n * E_;
  const float* src;
  if (e == 0)      src = q + (long)n * D_;
  else if (e < 5)  src = para + (long)(n * 4 + (e - 1)) * D_;
  else if (e < 45) src = sent + (long)(n * 40 + (e - 5)) * D_;
  else             src = ent + (long)(n * 60 + (e - 45)) * D_;
  float4 v0 = *(const float4*)(src + dc * 8);
  float4 v1 = *(const float4*)(src + dc * 8 + 4);
  uint4 o;
  o.x = (unsigned)f2b(v0.x) | ((unsigned)f2b(v0.y) << 16);
  o.y = (unsigned)f2b(v0.z) | ((unsigned)f2b(v0.w) << 16);
  o.z = (unsigned)f2b(v1.x) | ((unsigned)f2b(v1.y) << 16);
  o.w = (unsigned)f2b(v1.z) | ((unsigned)f2b(v1.w) << 16);
  *(uint4*)(x + (long)ne * D_ + dc * 8) = o;
  if (dc == 0) {
    float mv;
    if (e == 0)      mv = 1.f;
    else if (e < 5)  mv = pm[n * 4 + e - 1];
    else if (e < 45) mv = sm[n * 40 + e - 5];
    else             mv = em[n * 60 + e - 45];
    nmask[ne] = mv;
  }
}

// ---------------------------------------------------------------------------
// k_tr: dst[b][c][r] = bf16(src[b][r][c])   (R,C multiples of 32)
// ---------------------------------------------------------------------------
__global__ __launch_bounds__(256) void k_tr(const float* src, u16* dst, int R, int C,
                                            long sStr, long dStr) {
  __shared__ u16 t[32][33];
  const int bz = blockIdx.y;
  const int tilesC = C >> 5;
  const int tr = (blockIdx.x / tilesC) << 5;
  const int tc = (blockIdx.x % tilesC) << 5;
  const int lr = threadIdx.x >> 5;
  const int lc = threadIdx.x & 31;
#pragma unroll
  for (int i = 0; i < 4; ++i)
    t[lr + i * 8][lc] = f2b(src[bz * sStr + (long)(tr + lr + i * 8) * C + tc + lc]);
  __syncthreads();
#pragma unroll
  for (int i = 0; i < 4; ++i)
    dst[bz * dStr + (long)(tc + lr + i * 8) * R + tr + lc] = t[lc][lr + i * 8];
}

// ---------------------------------------------------------------------------
// k_qw1: r[ht][n][m] = relu( qb @ qW1t[ht]^T )      96 blocks
// ---------------------------------------------------------------------------
__global__ __launch_bounds__(256) void k_qw1(const u16* qb, const u16* qW1t, u16* r_bf) {
  const int bx = blockIdx.x;
  const int ht = bx >> 2, nt = (bx >> 1) & 1, mt = bx & 1;
  f32x4 acc[4][4];
  zero_acc(acc);
  gemm128(qb + (long)nt * 128 * D_, qW1t + ((long)ht * 256 + mt * 128) * D_, 1024, 1024, 1024, acc);
  const int tid = threadIdx.x, lane = tid & 63, wave = tid >> 6;
  const int ln15 = lane & 15, lq = lane >> 4;
  const int wRow = (wave >> 1) * 64, wCol = (wave & 1) * 64;
#pragma unroll
  for (int rt = 0; rt < 4; ++rt)
#pragma unroll
    for (int ct = 0; ct < 4; ++ct)
#pragma unroll
      for (int rg = 0; rg < 4; ++rg) {
        int n = nt * 128 + wRow + rt * 16 + lq * 4 + rg;
        int m = mt * 128 + wCol + ct * 16 + ln15;
        float v = acc[rt][ct][rg];
        if (v < 0.f) v = 0.f;
        r_bf[((long)ht * 256 + n) * 256 + m] = f2b(v);
      }
}

// ---------------------------------------------------------------------------
// k_qw2: ga[c][n][k] = sigmoid(r @ qW2t[ht]^T) * a[ht]      96 blocks
// ---------------------------------------------------------------------------
__global__ __launch_bounds__(256) void k_qw2(const u16* r_bf, const u16* qW2t, const float* a,
                                             u16* ga) {
  const int bx = blockIdx.x;
  const int ht = bx >> 2, nt = (bx >> 1) & 1, mt = bx & 1;
  f32x4 acc[4][4];
  zero_acc(acc);
  gemm128(r_bf + ((long)ht * 256 + nt * 128) * 256, qW2t + ((long)ht * 256 + mt * 128) * 256,
          256, 256, 256, acc);
  const int tid = threadIdx.x, lane = tid & 63, wave = tid >> 6;
  const int ln15 = lane & 15, lq = lane >> 4;
  const int wRow = (wave >> 1) * 64, wCol = (wave & 1) * 64;
#pragma unroll
  for (int rt = 0; rt < 4; ++rt)
#pragma unroll
    for (int ct = 0; ct < 4; ++ct)
#pragma unroll
      for (int rg = 0; rg < 4; ++rg) {
        int n = nt * 128 + wRow + rt * 16 + lq * 4 + rg;
        int m = mt * 128 + wCol + ct * 16 + ln15;
        float v = acc[rt][ct][rg];
        float sig = 1.f / (1.f + __expf(-v));
        float gv = sig * a[ht * 256 + m];
        int s = m >> 7, kk = m & 127;
        ga[(((long)ht * 2 + s) * 256 + n) * 128 + kk] = f2b(gv);
      }
}

// ---------------------------------------------------------------------------
// k_w12: w12[n][c][d] = sum_k ga[c][n][k] * W[ht][d][k]    768 blocks
// ---------------------------------------------------------------------------
__global__ __launch_bounds__(256) void k_w12(const u16* ga, const u16* Wb, u16* w12) {
  const int bx = blockIdx.x;
  const int c = bx >> 4, r2 = bx & 15;
  const int nt = r2 >> 3, dt = r2 & 7;
  const int ht = c >> 1;
  f32x4 acc[4][4];
  zero_acc(acc);
  gemm128(ga + ((long)c * 256 + nt * 128) * 128, Wb + (long)ht * 131072 + dt * 128 * 128,
          128, 128, 128, acc);
  const int tid = threadIdx.x, lane = tid & 63, wave = tid >> 6;
  const int ln15 = lane & 15, lq = lane >> 4;
  const int wRow = (wave >> 1) * 64, wCol = (wave & 1) * 64;
#pragma unroll
  for (int rt = 0; rt < 4; ++rt)
#pragma unroll
    for (int ct = 0; ct < 4; ++ct)
#pragma unroll
      for (int rg = 0; rg < 4; ++rg) {
        int n = nt * 128 + wRow + rt * 16 + lq * 4 + rg;
        int d = dt * 128 + wCol + ct * 16 + ln15;
        w12[((long)n * 48 + c) * 1024 + d] = f2b(acc[rt][ct][rg]);
      }
}

// ---------------------------------------------------------------------------
// k_f: F[n][c][e] = sum_d x[n][e][d] * w12[n][c][d]     256 blocks (padded 128x128)
// ---------------------------------------------------------------------------
__global__ __launch_bounds__(256) void k_f(const u16* x, const u16* w12, float* F) {
  const int n = blockIdx.x;
  f32x4 acc[4][4];
  zero_acc(acc);
  gemm128(x + (long)n * E_ * D_, w12 + (long)n * 48 * 1024, 1024, 1024, 1024, acc);
  const int tid = threadIdx.x, lane = tid & 63, wave = tid >> 6;
  const int ln15 = lane & 15, lq = lane >> 4;
  const int wRow = (wave >> 1) * 64, wCol = (wave & 1) * 64;
#pragma unroll
  for (int rt = 0; rt < 4; ++rt)
#pragma unroll
    for (int ct = 0; ct < 4; ++ct)
#pragma unroll
      for (int rg = 0; rg < 4; ++rg) {
        int e = wRow + rt * 16 + lq * 4 + rg;
        int c = wCol + ct * 16 + ln15;
        if (e < 105 && c < 48) F[((long)n * 48 + c) * 105 + e] = acc[rt][ct][rg];
      }
}

// ---------------------------------------------------------------------------
// k_h: h_last -> d_out (f32).  out[ne][h*128+k] = nmask[ne]*sum_d x[ne][d]*W[h,2][d][k]
// 1680 blocks (8 h x 210 ne-tiles)
// ---------------------------------------------------------------------------
__global__ __launch_bounds__(256) void k_h(const u16* x, const u16* Wt, const float* nmask,
                                           float* out) {
  const int bx = blockIdx.x;
  const int h = bx / 210;
  const int ne0 = (bx % 210) * 128;
  f32x4 acc[4][4];
  zero_acc(acc);
  gemm128(x + (long)ne0 * D_, Wt + (long)h * DH_ * D_, 1024, 1024, 1024, acc);
  const int tid = threadIdx.x, lane = tid & 63, wave = tid >> 6;
  const int ln15 = lane & 15, lq = lane >> 4;
  const int wRow = (wave >> 1) * 64, wCol = (wave & 1) * 64;
#pragma unroll
  for (int rt = 0; rt < 4; ++rt)
#pragma unroll
    for (int ct = 0; ct < 4; ++ct)
#pragma unroll
      for (int rg = 0; rg < 4; ++rg) {
        int ne = ne0 + wRow + rt * 16 + lq * 4 + rg;
        int k = wCol + ct * 16 + ln15;
        float mv = nmask[ne];
        out[(long)ne * D_ + h * DH_ + k] = acc[rt][ct][rg] * mv;
      }
}

// ---------------------------------------------------------------------------
// k_attn: per (h,n): scores from f1/f2/adj -> softmax -> coefs(bf16) @ h_last -> relu + x
// h_last read from d_out f32 (same region this block later overwrites). 2048 blocks.
// LDS: cb 28.7KB + hT 32.8KB + f 2.5KB = 64.0KB
// ---------------------------------------------------------------------------
__global__ __launch_bounds__(256) void k_attn(const float* F, const int* adj, const u16* x,
                                              float* out) {
  const int h = blockIdx.x >> 8;
  const int n = blockIdx.x & 255;
  __shared__ u16 cb[112 * 128];   // coefs bf16, 4-bit XOR swizzled rows
  __shared__ u16 hT[128 * 128];   // h_last transposed [k][j], swizzled
  __shared__ float f1s[3][105];
  __shared__ float f2s[3][105];
  const int tid = threadIdx.x;

  // ---- phase A ----
  for (int i = tid; i < 630; i += 256) {
    int t = i / 210;
    int rm = i - t * 210;
    int s = rm / 105;
    int e = rm - s * 105;
    float v = F[((long)n * 48 + (h * 3 + t) * 2 + s) * 105 + e];
    if (s == 0) f1s[t][e] = v; else f2s[t][e] = v;
  }
  for (int i = tid; i < 112 * 128; i += 256) cb[i] = 0;
  for (int i = tid; i < 105 * 32; i += 256) {
    int j = i >> 5, kc = i & 31;
    float4 v = *(const float4*)(out + ((long)(n * 105 + j)) * D_ + h * DH_ + kc * 4);
    int jc = j >> 3, jl = j & 7;
    int k0 = kc * 4;
    hT[(k0 + 0) * 128 + ((jc ^ ((k0 + 0) & 15)) << 3) + jl] = f2b(v.x);
    hT[(k0 + 1) * 128 + ((jc ^ ((k0 + 1) & 15)) << 3) + jl] = f2b(v.y);
    hT[(k0 + 2) * 128 + ((jc ^ ((k0 + 2) & 15)) << 3) + jl] = f2b(v.z);
    hT[(k0 + 3) * 128 + ((jc ^ ((k0 + 3) & 15)) << 3) + jl] = f2b(v.w);
  }
  for (int i = tid; i < 128 * 23; i += 256) {
    int k = i / 23;
    int j = 105 + (i - k * 23);
    int jc = j >> 3, jl = j & 7;
    hT[k * 128 + ((jc ^ (k & 15)) << 3) + jl] = 0;
  }
  __syncthreads();

  // ---- phase B: per-row softmax ----
  if (tid < 105) {
    const int* arow = adj + (long)n * 11025 + tid * 105;
    float m = -3.4e38f;
    for (int j = 0; j < 105; ++j) {
      int av = arow[j];
      float s;
      if (av > 0) {
        s = f1s[av - 1][tid] + f2s[av - 1][j];
        s = s < 0.f ? 0.2f * s : s;
      } else s = -1e30f;
      m = fmaxf(m, s);
    }
    float sum = 0.f;
    const int rsw = tid & 15;
    for (int j = 0; j < 105; ++j) {
      int av = arow[j];
      float s;
      if (av > 0) {
        s = f1s[av - 1][tid] + f2s[av - 1][j];
        s = s < 0.f ? 0.2f * s : s;
      } else s = -1e30f;
      float e = __expf(s - m);
      sum += e;
      int jc = j >> 3, jl = j & 7;
      cb[tid * 128 + ((jc ^ rsw) << 3) + jl] = f2b(e);
    }
    float inv = 1.f / sum;
    for (int j = 0; j < 105; ++j) {
      int jc = j >> 3, jl = j & 7;
      int off = tid * 128 + ((jc ^ rsw) << 3) + jl;
      cb[off] = f2b(b2f(cb[off]) * inv);
    }
  }
  __syncthreads();

  // ---- phase C: out[i][k] = sum_j coefs[i][j]*hl[j][k] via MFMA ----
  const int lane = tid & 63, wave = tid >> 6;
  const int ln15 = lane & 15, lq = lane >> 4;
  const int nmt = (wave < 3) ? 2 : 1;  // waves 0-2: mtiles {w,w+4}; wave 3: {3}
  f32x4 acc[2][8];
  {
    f32x4 z = {0.f, 0.f, 0.f, 0.f};
#pragma unroll
    for (int a_ = 0; a_ < 2; ++a_)
#pragma unroll
      for (int b_ = 0; b_ < 8; ++b_) acc[a_][b_] = z;
  }
#pragma unroll
  for (int ks = 0; ks < 4; ++ks) {
    const int cc = ks * 4 + lq;
    bf16x8 bfr[8];
#pragma unroll
    for (int jn = 0; jn < 8; ++jn) {
      int k = jn * 16 + ln15;
      bfr[jn] = *(const bf16x8*)&hT[k * 128 + ((cc ^ (k & 15)) << 3)];
    }
#pragma unroll
    for (int im = 0; im < 2; ++im) {
      if (im < nmt) {
        int i = (wave + im * 4) * 16 + ln15;
        bf16x8 af = *(const bf16x8*)&cb[i * 128 + ((cc ^ (i & 15)) << 3)];
#pragma unroll
        for (int jn = 0; jn < 8; ++jn)
          acc[im][jn] = __builtin_amdgcn_mfma_f32_16x16x32_bf16(af, bfr[jn], acc[im][jn], 0, 0, 0);
      }
    }
  }
  for (int im = 0; im < nmt; ++im)
    for (int jn = 0; jn < 8; ++jn)
#pragma unroll
      for (int rg = 0; rg < 4; ++rg) {
        int i = (wave + im * 4) * 16 + lq * 4 + rg;
        if (i < 105) {
          int k = jn * 16 + ln15;
          long off = ((long)(n * 105 + i)) * D_ + h * DH_ + k;
          float v = acc[im][jn][rg];
          v = v < 0.f ? 0.f : v;
          out[off] = v + b2f(x[off]);
        }
      }
}

// ---------------------------------------------------------------------------
extern "C" void kernel_launch(void* const* d_in, const int* in_sizes, int n_in,
                              void* d_out, int out_size, void* d_ws, size_t ws_size,
                              hipStream_t stream) {
  const float* q    = (const float*)d_in[0];
  const float* para = (const float*)d_in[1];
  const float* sent = (const float*)d_in[2];
  const float* ent  = (const float*)d_in[3];
  const float* pm   = (const float*)d_in[4];
  const float* sm   = (const float*)d_in[5];
  const float* em   = (const float*)d_in[6];
  const int*   adj  = (const int*)d_in[7];
  const float* W    = (const float*)d_in[8];
  const float* a    = (const float*)d_in[9];
  const float* qW1  = (const float*)d_in[10];
  const float* qW2  = (const float*)d_in[11];
  float* out = (float*)d_out;
  char* ws = (char*)d_ws;

  u16*   x     = (u16*)(ws);
  float* nmask = (float*)(ws + 55050240);
  u16*   qb    = (u16*)(ws + 55157760);
  u16*   Wb    = (u16*)(ws + 55682048);
  u16*   Wt    = (u16*)(ws + 61973504);
  u16*   qW1t  = (u16*)(ws + 64070656);
  u16*   qW2t  = (u16*)(ws + 76653568);
  u16*   r_bf  = (u16*)(ws + 79799296);
  u16*   ga    = (u16*)(ws + 82945024);
  u16*   w12   = (u16*)(ws + 86090752);
  float* F     = (float*)(ws + 111420416);

  k_build<<<13440, 256, 0, stream>>>(q, para, sent, ent, pm, sm, em, x, nmask);
  k_cast<<<256, 256, 0, stream>>>(q, qb, 262144);
  k_cast<<<3072, 256, 0, stream>>>(W, Wb, 3145728);
  k_tr<<<dim3(256, 24), 256, 0, stream>>>(qW1, qW1t, 1024, 256, 262144, 262144);
  k_tr<<<dim3(64, 24), 256, 0, stream>>>(qW2, qW2t, 256, 256, 65536, 65536);
  k_tr<<<dim3(128, 8), 256, 0, stream>>>(W + 262144, Wt, 1024, 128, 393216, 131072);
  k_qw1<<<96, 256, 0, stream>>>(qb, qW1t, r_bf);
  k_qw2<<<96, 256, 0, stream>>>(r_bf, qW2t, a, ga);
  k_w12<<<768, 256, 0, stream>>>(ga, Wb, w12);
  k_f<<<256, 256, 0, stream>>>(x, w12, F);
  k_h<<<1680, 256, 0, stream>>>(x, Wt, nmask, out);
  k_attn<<<2048, 256, 0, stream>>>(F, adj, x, out);
}

// Round 4
// 707.007 us; speedup vs baseline: 1.1719x; 1.1719x over previous
//
#include <hip/hip_runtime.h>
#include <stdint.h>

// GraphBlock_231928234690 — MI355X/gfx950, round 3
// f32 I/O; internal bf16 MFMA. h_last staged f32 inside d_out (proven in r2:
// block (h,n) reads exactly the d_out region it later overwrites — no aliasing).
// ws layout = round-2 proven layout (high water 116,581,376 B):
//   x     @ 0          : 26880*1024 bf16
//   nmask @ 55050240   : 26880 f32
//   (qb   @ 55157760   : unused this round, kept for layout stability)
//   Wb    @ 55682048   : 24*1024*128 bf16
//   Wt    @ 61973504   : 8*128*1024 bf16
//   qW1t  @ 64070656   : 24*256*1024 bf16
//   qW2t  @ 76653568   : 24*256*256 bf16
//   r_bf  @ 79799296   : 24*256*256 bf16
//   ga    @ 82945024   : 48*256*128 bf16
//   w12   @ 86090752   : 256*48*1024 bf16 (+slack for k_f B overread)
//   F     @ 111420416  : 256*48*105 f32

typedef unsigned short u16;
typedef __bf16 bf16;
typedef __bf16 bf16x8 __attribute__((ext_vector_type(8)));
typedef float f32x4 __attribute__((ext_vector_type(4)));

#define N_ 256
#define E_ 105
#define D_ 1024
#define H_ 8
#define DH_ 128
#define NE_ 26880

__device__ __forceinline__ u16 f2b(float f) { bf16 h = (bf16)f; return __builtin_bit_cast(u16, h); }
__device__ __forceinline__ float b2f(u16 u) { bf16 h = __builtin_bit_cast(bf16, u); return (float)h; }

#define AS1 __attribute__((address_space(1)))
#define AS3 __attribute__((address_space(3)))

__device__ __forceinline__ void load16_lds(const void* g, void* l) {
  __builtin_amdgcn_global_load_lds((AS1 void*)(unsigned long long)(uintptr_t)g,
                                   (AS3 void*)l, 16, 0, 0);
}

// ---------------------------------------------------------------------------
// 128x128 bf16 GEMM tile: C[128r x 128c] = A(128 x K) * B(128 x K)^T
// ---------------------------------------------------------------------------
__device__ __forceinline__ void gemm128(const u16* A, const u16* B, int K,
                                        int lda, int ldb, f32x4 (&acc)[4][4]) {
  __shared__ u16 lA[8192];
  __shared__ u16 lB[8192];
  const int tid  = threadIdx.x;
  const int lane = tid & 63;
  const int wave = tid >> 6;
  const int ln15 = lane & 15;
  const int lq   = lane >> 4;
  const int wRow = (wave >> 1) * 64;
  const int wCol = (wave & 1) * 64;

  const int iters = K >> 6;
  for (int kt = 0; kt < iters; ++kt) {
    const char* Ab = (const char*)A + kt * 128;
    const char* Bb = (const char*)B + kt * 128;
#pragma unroll
    for (int m = 0; m < 4; ++m) {
      int ci  = m * 256 + tid;
      int row = ci >> 3;
      int g   = (ci & 7) ^ (row & 7);
      char* dstA = (char*)lA + m * 4096 + wave * 1024;
      char* dstB = (char*)lB + m * 4096 + wave * 1024;
      load16_lds(Ab + (long)row * ((long)lda * 2) + g * 16, dstA);
      load16_lds(Bb + (long)row * ((long)ldb * 2) + g * 16, dstB);
    }
    __syncthreads();
#pragma unroll
    for (int ks = 0; ks < 2; ++ks) {
      const int cc = ks * 4 + lq;
      bf16x8 af[4], bfv[4];
#pragma unroll
      for (int i = 0; i < 4; ++i) {
        int r = wRow + i * 16 + ln15;
        af[i] = *(const bf16x8*)&lA[r * 64 + ((cc ^ (r & 7)) << 3)];
        int c = wCol + i * 16 + ln15;
        bfv[i] = *(const bf16x8*)&lB[c * 64 + ((cc ^ (c & 7)) << 3)];
      }
#pragma unroll
      for (int i = 0; i < 4; ++i)
#pragma unroll
        for (int j = 0; j < 4; ++j)
          acc[i][j] = __builtin_amdgcn_mfma_f32_16x16x32_bf16(af[i], bfv[j], acc[i][j], 0, 0, 0);
    }
    __syncthreads();
  }
}

__device__ __forceinline__ void zero_acc(f32x4 (&acc)[4][4]) {
  f32x4 z = {0.f, 0.f, 0.f, 0.f};
#pragma unroll
  for (int i = 0; i < 4; ++i)
#pragma unroll
    for (int j = 0; j < 4; ++j) acc[i][j] = z;
}

// ---------------------------------------------------------------------------
__global__ __launch_bounds__(256) void k_cast(const float* src, u16* dst, long n) {
  long i = ((long)blockIdx.x * 256 + threadIdx.x) * 4;
  if (i >= n) return;
  float4 v = *(const float4*)(src + i);
  ushort4 o;
  o.x = f2b(v.x); o.y = f2b(v.y); o.z = f2b(v.z); o.w = f2b(v.w);
  *(ushort4*)(dst + i) = o;
}

// ---------------------------------------------------------------------------
__global__ __launch_bounds__(256) void k_build(const float* q, const float* para,
                                               const float* sent, const float* ent,
                                               const float* pm, const float* sm,
                                               const float* em, u16* x, float* nmask) {
  long idx = (long)blockIdx.x * 256 + threadIdx.x;
  if (idx >= (long)NE_ * 128) return;
  int ne = (int)(idx >> 7), dc = (int)(idx & 127);
  int n = ne / E_, e = ne - n * E_;
  const float* src;
  if (e == 0)      src = q + (long)n * D_;
  else if (e < 5)  src = para + (long)(n * 4 + (e - 1)) * D_;
  else if (e < 45) src = sent + (long)(n * 40 + (e - 5)) * D_;
  else             src = ent + (long)(n * 60 + (e - 45)) * D_;
  float4 v0 = *(const float4*)(src + dc * 8);
  float4 v1 = *(const float4*)(src + dc * 8 + 4);
  uint4 o;
  o.x = (unsigned)f2b(v0.x) | ((unsigned)f2b(v0.y) << 16);
  o.y = (unsigned)f2b(v0.z) | ((unsigned)f2b(v0.w) << 16);
  o.z = (unsigned)f2b(v1.x) | ((unsigned)f2b(v1.y) << 16);
  o.w = (unsigned)f2b(v1.z) | ((unsigned)f2b(v1.w) << 16);
  *(uint4*)(x + (long)ne * D_ + dc * 8) = o;
  if (dc == 0) {
    float mv;
    if (e == 0)      mv = 1.f;
    else if (e < 5)  mv = pm[n * 4 + e - 1];
    else if (e < 45) mv = sm[n * 40 + e - 5];
    else             mv = em[n * 60 + e - 45];
    nmask[ne] = mv;
  }
}

// ---------------------------------------------------------------------------
__global__ __launch_bounds__(256) void k_tr(const float* src, u16* dst, int R, int C,
                                            long sStr, long dStr) {
  __shared__ u16 t[32][33];
  const int bz = blockIdx.y;
  const int tilesC = C >> 5;
  const int tr = (blockIdx.x / tilesC) << 5;
  const int tc = (blockIdx.x % tilesC) << 5;
  const int lr = threadIdx.x >> 5;
  const int lc = threadIdx.x & 31;
#pragma unroll
  for (int i = 0; i < 4; ++i)
    t[lr + i * 8][lc] = f2b(src[bz * sStr + (long)(tr + lr + i * 8) * C + tc + lc]);
  __syncthreads();
#pragma unroll
  for (int i = 0; i < 4; ++i)
    dst[bz * dStr + (long)(tc + lr + i * 8) * R + tr + lc] = t[lc][lr + i * 8];
}

// ---------------------------------------------------------------------------
// k_qw1: r[ht][n][m] = relu( x(e=0 rows, lda=105*1024) @ qW1t[ht]^T )  96 blocks
// ---------------------------------------------------------------------------
__global__ __launch_bounds__(256) void k_qw1(const u16* x, const u16* qW1t, u16* r_bf) {
  const int bx = blockIdx.x;
  const int ht = bx >> 2, nt = (bx >> 1) & 1, mt = bx & 1;
  f32x4 acc[4][4];
  zero_acc(acc);
  gemm128(x + (long)nt * 128 * (E_ * D_), qW1t + ((long)ht * 256 + mt * 128) * D_,
          1024, E_ * D_, 1024, acc);
  const int tid = threadIdx.x, lane = tid & 63, wave = tid >> 6;
  const int ln15 = lane & 15, lq = lane >> 4;
  const int wRow = (wave >> 1) * 64, wCol = (wave & 1) * 64;
#pragma unroll
  for (int rt = 0; rt < 4; ++rt)
#pragma unroll
    for (int ct = 0; ct < 4; ++ct)
#pragma unroll
      for (int rg = 0; rg < 4; ++rg) {
        int n = nt * 128 + wRow + rt * 16 + lq * 4 + rg;
        int m = mt * 128 + wCol + ct * 16 + ln15;
        float v = acc[rt][ct][rg];
        if (v < 0.f) v = 0.f;
        r_bf[((long)ht * 256 + n) * 256 + m] = f2b(v);
      }
}

// ---------------------------------------------------------------------------
__global__ __launch_bounds__(256) void k_qw2(const u16* r_bf, const u16* qW2t, const float* a,
                                             u16* ga) {
  const int bx = blockIdx.x;
  const int ht = bx >> 2, nt = (bx >> 1) & 1, mt = bx & 1;
  f32x4 acc[4][4];
  zero_acc(acc);
  gemm128(r_bf + ((long)ht * 256 + nt * 128) * 256, qW2t + ((long)ht * 256 + mt * 128) * 256,
          256, 256, 256, acc);
  const int tid = threadIdx.x, lane = tid & 63, wave = tid >> 6;
  const int ln15 = lane & 15, lq = lane >> 4;
  const int wRow = (wave >> 1) * 64, wCol = (wave & 1) * 64;
#pragma unroll
  for (int rt = 0; rt < 4; ++rt)
#pragma unroll
    for (int ct = 0; ct < 4; ++ct)
#pragma unroll
      for (int rg = 0; rg < 4; ++rg) {
        int n = nt * 128 + wRow + rt * 16 + lq * 4 + rg;
        int m = mt * 128 + wCol + ct * 16 + ln15;
        float v = acc[rt][ct][rg];
        float sig = 1.f / (1.f + __expf(-v));
        float gv = sig * a[ht * 256 + m];
        int s = m >> 7, kk = m & 127;
        ga[(((long)ht * 2 + s) * 256 + n) * 128 + kk] = f2b(gv);
      }
}

// ---------------------------------------------------------------------------
__global__ __launch_bounds__(256) void k_w12(const u16* ga, const u16* Wb, u16* w12) {
  const int bx = blockIdx.x;
  const int c = bx >> 4, r2 = bx & 15;
  const int nt = r2 >> 3, dt = r2 & 7;
  const int ht = c >> 1;
  f32x4 acc[4][4];
  zero_acc(acc);
  gemm128(ga + ((long)c * 256 + nt * 128) * 128, Wb + (long)ht * 131072 + dt * 128 * 128,
          128, 128, 128, acc);
  const int tid = threadIdx.x, lane = tid & 63, wave = tid >> 6;
  const int ln15 = lane & 15, lq = lane >> 4;
  const int wRow = (wave >> 1) * 64, wCol = (wave & 1) * 64;
#pragma unroll
  for (int rt = 0; rt < 4; ++rt)
#pragma unroll
    for (int ct = 0; ct < 4; ++ct)
#pragma unroll
      for (int rg = 0; rg < 4; ++rg) {
        int n = nt * 128 + wRow + rt * 16 + lq * 4 + rg;
        int d = dt * 128 + wCol + ct * 16 + ln15;
        w12[((long)n * 48 + c) * 1024 + d] = f2b(acc[rt][ct][rg]);
      }
}

// ---------------------------------------------------------------------------
__global__ __launch_bounds__(256) void k_f(const u16* x, const u16* w12, float* F) {
  const int n = blockIdx.x;
  f32x4 acc[4][4];
  zero_acc(acc);
  gemm128(x + (long)n * E_ * D_, w12 + (long)n * 48 * 1024, 1024, 1024, 1024, acc);
  const int tid = threadIdx.x, lane = tid & 63, wave = tid >> 6;
  const int ln15 = lane & 15, lq = lane >> 4;
  const int wRow = (wave >> 1) * 64, wCol = (wave & 1) * 64;
#pragma unroll
  for (int rt = 0; rt < 4; ++rt)
#pragma unroll
    for (int ct = 0; ct < 4; ++ct)
#pragma unroll
      for (int rg = 0; rg < 4; ++rg) {
        int e = wRow + rt * 16 + lq * 4 + rg;
        int c = wCol + ct * 16 + ln15;
        if (e < 105 && c < 48) F[((long)n * 48 + c) * 105 + e] = acc[rt][ct][rg];
      }
}

// ---------------------------------------------------------------------------
// k_h: h_last -> d_out (f32).  out[ne][h*128+k] = nmask[ne]*sum_d x[ne][d]*W[h,2][d][k]
// ---------------------------------------------------------------------------
__global__ __launch_bounds__(256) void k_h(const u16* x, const u16* Wt, const float* nmask,
                                           float* out) {
  const int bx = blockIdx.x;
  const int h = bx / 210;
  const int ne0 = (bx % 210) * 128;
  f32x4 acc[4][4];
  zero_acc(acc);
  gemm128(x + (long)ne0 * D_, Wt + (long)h * DH_ * D_, 1024, 1024, 1024, acc);
  const int tid = threadIdx.x, lane = tid & 63, wave = tid >> 6;
  const int ln15 = lane & 15, lq = lane >> 4;
  const int wRow = (wave >> 1) * 64, wCol = (wave & 1) * 64;
#pragma unroll
  for (int rt = 0; rt < 4; ++rt)
#pragma unroll
    for (int ct = 0; ct < 4; ++ct)
#pragma unroll
      for (int rg = 0; rg < 4; ++rg) {
        int ne = ne0 + wRow + rt * 16 + lq * 4 + rg;
        int k = wCol + ct * 16 + ln15;
        float mv = nmask[ne];
        out[(long)ne * D_ + h * DH_ + k] = acc[rt][ct][rg] * mv;
      }
}

// ---------------------------------------------------------------------------
// k_attn: per (h,n): wave-parallel softmax (adj coalesced, shfl butterflies)
// -> coefs bf16 -> MFMA PV -> relu -> +x residual. 2048 blocks.
// h_last read from d_out f32 (block reads exactly its own region).
// ---------------------------------------------------------------------------
__global__ __launch_bounds__(256) void k_attn(const float* F, const int* adj, const u16* x,
                                              float* out) {
  const int h = blockIdx.x >> 8;
  const int n = blockIdx.x & 255;
  __shared__ u16 cb[112 * 128];
  __shared__ u16 hT[128 * 128];
  __shared__ float f1s[3][112];
  __shared__ float f2s[3][112];
  const int tid = threadIdx.x;
  const int lane = tid & 63, wave = tid >> 6;

  // ---- phase A: stage F rows, zero cb, transpose h_last (from out) -> hT ----
  for (int i = tid; i < 630; i += 256) {
    int t = i / 210;
    int rm = i - t * 210;
    int s = rm / 105;
    int e = rm - s * 105;
    float v = F[((long)n * 48 + (h * 3 + t) * 2 + s) * 105 + e];
    if (s == 0) f1s[t][e] = v; else f2s[t][e] = v;
  }
  {
    unsigned* cbz = (unsigned*)cb;
    for (int i = tid; i < 112 * 64; i += 256) cbz[i] = 0;
  }
  for (int i = tid; i < 105 * 32; i += 256) {
    int j = i >> 5, kc = i & 31;
    float4 v = *(const float4*)(out + ((long)(n * 105 + j)) * D_ + h * DH_ + kc * 4);
    int jc = j >> 3, jl = j & 7;
    int k0 = kc * 4;
    hT[(k0 + 0) * 128 + ((jc ^ ((k0 + 0) & 15)) << 3) + jl] = f2b(v.x);
    hT[(k0 + 1) * 128 + ((jc ^ ((k0 + 1) & 15)) << 3) + jl] = f2b(v.y);
    hT[(k0 + 2) * 128 + ((jc ^ ((k0 + 2) & 15)) << 3) + jl] = f2b(v.z);
    hT[(k0 + 3) * 128 + ((jc ^ ((k0 + 3) & 15)) << 3) + jl] = f2b(v.w);
  }
  for (int i = tid; i < 128 * 23; i += 256) {
    int k = i / 23;
    int j = 105 + (i - k * 23);
    int jc = j >> 3, jl = j & 7;
    hT[k * 128 + ((jc ^ (k & 15)) << 3) + jl] = 0;
  }
  __syncthreads();

  // ---- phase B: wave w owns rows i=w,w+4,..; lane owns cols j=lane, 64+lane ----
  {
    const int j1 = 64 + lane;
    float f20a = f2s[0][lane], f20b = f2s[1][lane], f20c = f2s[2][lane];
    float f21a = 0.f, f21b = 0.f, f21c = 0.f;
    if (lane < 41) { f21a = f2s[0][j1]; f21b = f2s[1][j1]; f21c = f2s[2][j1]; }
    for (int i = wave; i < 105; i += 4) {
      const int* arow = adj + (long)n * (E_ * E_) + i * E_;
      int av0 = arow[lane];
      int av1 = (lane < 41) ? arow[j1] : 0;
      float f11 = f1s[0][i], f12 = f1s[1][i], f13 = f1s[2][i];
      float s0, s1;
      {
        float f1v = (av0 == 1) ? f11 : ((av0 == 2) ? f12 : f13);
        float f2v = (av0 == 1) ? f20a : ((av0 == 2) ? f20b : f20c);
        float s = f1v + f2v;
        s = (s < 0.f) ? 0.2f * s : s;
        s0 = (av0 > 0) ? s : -1e30f;
      }
      {
        float f1v = (av1 == 1) ? f11 : ((av1 == 2) ? f12 : f13);
        float f2v = (av1 == 1) ? f21a : ((av1 == 2) ? f21b : f21c);
        float s = f1v + f2v;
        s = (s < 0.f) ? 0.2f * s : s;
        s1 = (av1 > 0) ? s : -1e30f;
      }
      float m = fmaxf(s0, s1);
#pragma unroll
      for (int d = 1; d < 64; d <<= 1) m = fmaxf(m, __shfl_xor(m, d));
      float e0 = __expf(s0 - m);
      float e1 = (lane < 41) ? __expf(s1 - m) : 0.f;
      float sum = e0 + e1;
#pragma unroll
      for (int d = 1; d < 64; d <<= 1) sum += __shfl_xor(sum, d);
      float inv = 1.f / sum;
      const int rsw = i & 15;
      cb[i * 128 + ((((lane >> 3) ^ rsw) << 3) + (lane & 7))] = f2b(e0 * inv);
      if (lane < 41)
        cb[i * 128 + ((((j1 >> 3) ^ rsw) << 3) + (lane & 7))] = f2b(e1 * inv);
    }
  }
  __syncthreads();

  // ---- phase C: out[i][k] = sum_j coefs[i][j]*hl[j][k] via MFMA; +relu +x ----
  const int ln15 = lane & 15, lq = lane >> 4;
  const int nmt = (wave < 3) ? 2 : 1;
  f32x4 acc[2][8];
  {
    f32x4 z = {0.f, 0.f, 0.f, 0.f};
#pragma unroll
    for (int a_ = 0; a_ < 2; ++a_)
#pragma unroll
      for (int b_ = 0; b_ < 8; ++b_) acc[a_][b_] = z;
  }
#pragma unroll
  for (int ks = 0; ks < 4; ++ks) {
    const int cc = ks * 4 + lq;
    bf16x8 bfr[8];
#pragma unroll
    for (int jn = 0; jn < 8; ++jn) {
      int k = jn * 16 + ln15;
      bfr[jn] = *(const bf16x8*)&hT[k * 128 + ((cc ^ (k & 15)) << 3)];
    }
#pragma unroll
    for (int im = 0; im < 2; ++im) {
      if (im < nmt) {
        int i = (wave + im * 4) * 16 + ln15;
        bf16x8 af = *(const bf16x8*)&cb[i * 128 + ((cc ^ (i & 15)) << 3)];
#pragma unroll
        for (int jn = 0; jn < 8; ++jn)
          acc[im][jn] = __builtin_amdgcn_mfma_f32_16x16x32_bf16(af, bfr[jn], acc[im][jn], 0, 0, 0);
      }
    }
  }
  for (int im = 0; im < nmt; ++im)
    for (int jn = 0; jn < 8; ++jn)
#pragma unroll
      for (int rg = 0; rg < 4; ++rg) {
        int i = (wave + im * 4) * 16 + lq * 4 + rg;
        if (i < 105) {
          int k = jn * 16 + ln15;
          long off = ((long)(n * E_ + i)) * D_ + h * DH_ + k;
          float v = acc[im][jn][rg];
          v = v < 0.f ? 0.f : v;
          out[off] = v + b2f(x[off]);
        }
      }
}

// ---------------------------------------------------------------------------
extern "C" void kernel_launch(void* const* d_in, const int* in_sizes, int n_in,
                              void* d_out, int out_size, void* d_ws, size_t ws_size,
                              hipStream_t stream) {
  const float* q    = (const float*)d_in[0];
  const float* para = (const float*)d_in[1];
  const float* sent = (const float*)d_in[2];
  const float* ent  = (const float*)d_in[3];
  const float* pm   = (const float*)d_in[4];
  const float* sm   = (const float*)d_in[5];
  const float* em   = (const float*)d_in[6];
  const int*   adj  = (const int*)d_in[7];
  const float* W    = (const float*)d_in[8];
  const float* a    = (const float*)d_in[9];
  const float* qW1  = (const float*)d_in[10];
  const float* qW2  = (const float*)d_in[11];
  float* out = (float*)d_out;
  char* ws = (char*)d_ws;

  u16*   x     = (u16*)(ws);
  float* nmask = (float*)(ws + 55050240);
  u16*   Wb    = (u16*)(ws + 55682048);
  u16*   Wt    = (u16*)(ws + 61973504);
  u16*   qW1t  = (u16*)(ws + 64070656);
  u16*   qW2t  = (u16*)(ws + 76653568);
  u16*   r_bf  = (u16*)(ws + 79799296);
  u16*   ga    = (u16*)(ws + 82945024);
  u16*   w12   = (u16*)(ws + 86090752);
  float* F     = (float*)(ws + 111420416);

  k_build<<<13440, 256, 0, stream>>>(q, para, sent, ent, pm, sm, em, x, nmask);
  k_cast<<<3072, 256, 0, stream>>>(W, Wb, 3145728);
  k_tr<<<dim3(256, 24), 256, 0, stream>>>(qW1, qW1t, 1024, 256, 262144, 262144);
  k_tr<<<dim3(64, 24), 256, 0, stream>>>(qW2, qW2t, 256, 256, 65536, 65536);
  k_tr<<<dim3(128, 8), 256, 0, stream>>>(W + 262144, Wt, 1024, 128, 393216, 131072);
  k_qw1<<<96, 256, 0, stream>>>(x, qW1t, r_bf);
  k_qw2<<<96, 256, 0, stream>>>(r_bf, qW2t, a, ga);
  k_w12<<<768, 256, 0, stream>>>(ga, Wb, w12);
  k_f<<<256, 256, 0, stream>>>(x, w12, F);
  k_h<<<1680, 256, 0, stream>>>(x, Wt, nmask, out);
  k_attn<<<2048, 256, 0, stream>>>(F, adj, x, out);
}